// Round 1
// 207.190 us; speedup vs baseline: 1.0056x; 1.0056x over previous
//
#include <hip/hip_runtime.h>

// YOLOv1 loss, faithful to the reference (including the in-place corner bug).
// R7: occupancy + latency restructure vs R6.
//  - No LDS staging: T is read per-lane as 15 float2 (row stride 120 B, 8-B
//    aligned). Every byte of the contiguous wave slab is demanded exactly once;
//    L1/L2 merge the sector requests, so HBM FETCH is unchanged vs staged-T,
//    but the ds_write + waitcnt + barrier serialization disappears.
//  - 256-thread blocks, __launch_bounds__(256, 8): 8 blocks/CU = 32 waves/CU
//    resident (2x R6's 16-wave cap from single-wave workgroups + LDS).
//  - One cell per thread, no hot-loop barriers: per-thread lifetime is one
//    load batch + one dependent gather; TLP (32 waves/CU) hides both.
//  - P scheme unchanged: cols 0..9 via five float2, p[kcol] via one dependent
//    8-B gather after the argmax (keeps P demand at ~48 B of 120 B per row).

constexpr int   BLK  = 256;
constexpr int   NC   = 16384 * 7 * 7;   // 802816 cells
constexpr int   GRID = NC / BLK;        // 3136 blocks, exact (no bounds check)
constexpr float CELL = 1.0f / 7.0f;
constexpr float LC   = 5.0f;
constexpr float LN   = 0.5f;

__launch_bounds__(BLK, 8)               // 8 waves/EU -> 32 waves/CU, VGPR <= 64
__global__ void yolo_partial(const float* __restrict__ P, const float* __restrict__ T,
                             float4* __restrict__ ws)
{
    const int tid  = threadIdx.x;
    const int cell = blockIdx.x * BLK + tid;
    const float* trow = T + (size_t)cell * 30;
    const float* prow = P + (size_t)cell * 30;

    // ---- one independent load batch: 15 float2 of T + 5 float2 of P ----
    float tv[30];
    #pragma unroll
    for (int j = 0; j < 15; ++j) {
        float2 v = reinterpret_cast<const float2*>(trow)[j];
        tv[2 * j] = v.x; tv[2 * j + 1] = v.y;
    }
    float pv[10];
    #pragma unroll
    for (int j = 0; j < 5; ++j) {
        float2 v = reinterpret_cast<const float2*>(prow)[j];
        pv[2 * j] = v.x; pv[2 * j + 1] = v.y;
    }

    // class column: argmax over t[10:30], first occurrence (strict >)
    int kc = 10;
    float best = tv[10];
    #pragma unroll
    for (int k = 11; k < 30; ++k) {
        if (tv[k] > best) { best = tv[k]; kc = k; }
    }
    // dependent 8-B gather for p[kc] (kc in [10,30)); issue early
    float2 pg = *reinterpret_cast<const float2*>(prow + (kc & ~1));
    float pk = (kc & 1) ? pg.y : pg.x;

    const float t4 = tv[4];
    const float obj   = (t4 == 1.0f) ? 1.0f : 0.0f;
    const float noobj = (t4 == 0.0f) ? 1.0f : 0.0f;

    float d4 = pv[4] - t4;
    float d9 = pv[9] - tv[9];
    float a_noobj = noobj * (d4 * d4 + d9 * d9);

    // target corners (faithful bug: x2 uses already-updated x1)
    float tw2 = tv[2] * tv[2], th2 = tv[3] * tv[3];
    float tx1 = tv[0] * CELL - 0.5f * tw2;
    float tx2 = tx1 * CELL + 0.5f * tw2;
    float ty1 = tv[1] * CELL - 0.5f * th2;
    float ty2 = ty1 * CELL + 0.5f * th2;
    float area_t = (tx2 - tx1) * (ty2 - ty1);

    float iou0, iou1;
    #pragma unroll
    for (int b = 0; b < 2; ++b) {
        float bw2 = pv[5 * b + 2] * pv[5 * b + 2];
        float bh2 = pv[5 * b + 3] * pv[5 * b + 3];
        float px1 = pv[5 * b + 0] * CELL - 0.5f * bw2;
        float px2 = px1 * CELL + 0.5f * bw2;
        float py1 = pv[5 * b + 1] * CELL - 0.5f * bh2;
        float py2 = py1 * CELL + 0.5f * bh2;
        float ltx = fmaxf(px1, tx1), lty = fmaxf(py1, ty1);
        float rbx = fminf(px2, tx2), rby = fminf(py2, ty2);
        float inter = fmaxf(rbx - ltx, 0.0f) * fmaxf(rby - lty, 0.0f);
        float area_p = (px2 - px1) * (py2 - py1);
        float iou = inter / (area_p + area_t - inter);
        if (b == 0) iou0 = iou; else iou1 = iou;
    }
    const bool b1 = (iou1 > iou0);   // jnp.argmax: first on ties

    float cpx = b1 ? pv[5] : pv[0], ctx = b1 ? tv[5] : tv[0];
    float cpy = b1 ? pv[6] : pv[1], cty = b1 ? tv[6] : tv[1];
    float cpw = b1 ? pv[7] : pv[2], ctw = b1 ? tv[7] : tv[2];
    float cph = b1 ? pv[8] : pv[3], cth = b1 ? tv[8] : tv[3];
    float cpc = b1 ? pv[9] : pv[4], ctc = b1 ? tv[9] : tv[4];

    float dx = cpx - ctx, dy = cpy - cty;
    float dw = cpw - ctw, dh = cph - cth;
    float a_cw   = obj * (dx * dx + dy * dy + dw * dw + dh * dh);
    float dc = cpc - ctc;
    float a_conf = obj * dc * dc;
    float dk = pk - best;
    float a_cls  = obj * dk * dk;

    // ---- block reduction: wave shuffle -> tiny LDS across 4 waves ----
    float vals[4] = { a_cls, a_conf, a_cw, a_noobj };
    #pragma unroll
    for (int c = 0; c < 4; ++c) {
        #pragma unroll
        for (int off = 32; off > 0; off >>= 1)
            vals[c] += __shfl_down(vals[c], off, 64);
    }
    __shared__ float red[4][4];
    const int wave = tid >> 6;
    if ((tid & 63) == 0) {
        red[0][wave] = vals[0]; red[1][wave] = vals[1];
        red[2][wave] = vals[2]; red[3][wave] = vals[3];
    }
    __syncthreads();
    if (tid == 0) {
        ws[blockIdx.x] = make_float4(
            red[0][0] + red[0][1] + red[0][2] + red[0][3],
            red[1][0] + red[1][1] + red[1][2] + red[1][3],
            red[2][0] + red[2][1] + red[2][2] + red[2][3],
            red[3][0] + red[3][1] + red[3][2] + red[3][3]);
    }
}

__launch_bounds__(1024, 1)
__global__ void yolo_reduce(const float4* __restrict__ ws, float* __restrict__ out)
{
    __shared__ float red[4][16];
    const int tid = threadIdx.x;

    float s0 = 0.f, s1 = 0.f, s2 = 0.f, s3 = 0.f;
    for (int b = tid; b < GRID; b += 1024) {    // coalesced float4 stream
        float4 v = ws[b];
        s0 += v.x; s1 += v.y; s2 += v.z; s3 += v.w;
    }
    float vals[4] = { s0, s1, s2, s3 };
    #pragma unroll
    for (int c = 0; c < 4; ++c) {
        #pragma unroll
        for (int off = 32; off > 0; off >>= 1)
            vals[c] += __shfl_down(vals[c], off, 64);
        if ((tid & 63) == 0) red[c][tid >> 6] = vals[c];
    }
    __syncthreads();
    if (tid == 0) {
        float t0 = 0.f, t1 = 0.f, t2 = 0.f, t3 = 0.f;
        #pragma unroll
        for (int w = 0; w < 16; ++w) {
            t0 += red[0][w]; t1 += red[1][w]; t2 += red[2][w]; t3 += red[3][w];
        }
        out[0] = LC * t0;                              // cls_loss
        out[1] = LC * t1;                              // conf_loss
        out[2] = LC * t2;                              // center+wh
        out[3] = LN * t3 + LC * (t0 + t1 + t2);        // total
    }
}

extern "C" void kernel_launch(void* const* d_in, const int* in_sizes, int n_in,
                              void* d_out, int out_size, void* d_ws, size_t ws_size,
                              hipStream_t stream) {
    const float* P = (const float*)d_in[0];
    const float* T = (const float*)d_in[1];
    float* out = (float*)d_out;
    float4* ws = (float4*)d_ws;          // GRID * 16 B = 50176 B of scratch

    yolo_partial<<<GRID, BLK, 0, stream>>>(P, T, ws);
    yolo_reduce<<<1, 1024, 0, stream>>>(ws, out);
}

// Round 2
// 205.518 us; speedup vs baseline: 1.0137x; 1.0081x over previous
//
#include <hip/hip_runtime.h>

// YOLOv1 loss, faithful to the reference (including the in-place corner bug).
// R8: coalescing restructure vs R7.
//   Diagnosis: R7's per-lane strided float2 loads (stride 120 B) make every
//   wave memory instruction touch ~64 distinct 64-B lines -> TA/L1 line-lookup
//   serialization is the bottleneck (HBM 16%, VALU 6%, occupancy 61%: all
//   pipes idle). Also, P's "cols 0..9 + gather" trick saves no LINES: the kc
//   gather spreads over bytes 40..119, so P line-demand ~= full array.
//   Fix: stream BOTH arrays fully coalesced into LDS via global_load_lds
//   width=16 (lane-contiguous float4: 16 lines/instr, no VGPR round trip),
//   then each thread reads its own 120-B row from LDS. All 30 P cols in
//   registers kills the dependent gather: pk rides the argmax select chain
//   (compile-time indices only -> no scratch).
//   128-thread blocks, 30.8 KB LDS -> 5 blocks/CU; staging of one block
//   overlaps compute of others. 2 tiles per block keeps ws at 50 KB.

constexpr int   BLK   = 128;            // 2 waves
constexpr int   TILE  = 128;            // cells per tile (1 cell/thread)
constexpr int   NC    = 16384 * 7 * 7;  // 802816 cells
constexpr int   NTILE = NC / TILE;      // 6272 tiles
constexpr int   GRID  = 3136;           // 2 tiles per block, exact
constexpr float CELL  = 1.0f / 7.0f;
constexpr float LC    = 5.0f;
constexpr float LN    = 0.5f;

__device__ inline void gload_lds16(const float4* g, float4* l)
{
    __builtin_amdgcn_global_load_lds(
        (const __attribute__((address_space(1))) void*)g,
        (__attribute__((address_space(3))) void*)l,
        16, 0, 0);
}

__launch_bounds__(BLK, 3)
__global__ void yolo_partial(const float* __restrict__ P, const float* __restrict__ T,
                             float4* __restrict__ ws)
{
    // [0,960) float4 = T tile (128 cells x 120 B), [960,1920) = P tile
    __shared__ float4 s4[1920];         // 30720 B
    __shared__ float red[4][2];

    const int tid = threadIdx.x;
    float a_cls = 0.f, a_conf = 0.f, a_cw = 0.f, a_noobj = 0.f;

    for (int t = blockIdx.x; t < NTILE; t += GRID) {
        const size_t fbase = (size_t)t * (TILE * 30);   // float offset of tile
        const float4* gT = reinterpret_cast<const float4*>(T + fbase);
        const float4* gP = reinterpret_cast<const float4*>(P + fbase);

        // ---- coalesced direct-to-LDS staging: 1920 float4, 15 per thread.
        //      960 is a multiple of 64, so no wave straddles the T/P switch;
        //      LDS dest is linear in lane order as global_load_lds requires.
        #pragma unroll
        for (int k = 0; k < 15; ++k) {
            const int idx = k * BLK + tid;              // 0..1919
            const float4* g = (idx < 960) ? (gT + idx) : (gP + (idx - 960));
            gload_lds16(g, s4 + idx);
        }
        __syncthreads();                // drains vmcnt(0): tile resident

        // ---- this thread's cell: 30 ds_read_b64 (T row + P row) ----
        const float* sf  = reinterpret_cast<const float*>(s4);
        const float* myT = sf + (size_t)tid * 30;
        const float* myP = sf + 3840 + (size_t)tid * 30;
        float tv[30], pv[30];
        #pragma unroll
        for (int j = 0; j < 15; ++j) {
            float2 a = reinterpret_cast<const float2*>(myT)[j];
            tv[2 * j] = a.x; tv[2 * j + 1] = a.y;
            float2 b = reinterpret_cast<const float2*>(myP)[j];
            pv[2 * j] = b.x; pv[2 * j + 1] = b.y;
        }

        // argmax over t[10:30] with p-payload, first occurrence (strict >)
        float best = tv[10], pk = pv[10];
        #pragma unroll
        for (int k = 11; k < 30; ++k) {
            if (tv[k] > best) { best = tv[k]; pk = pv[k]; }
        }

        const float t4    = tv[4];
        const float obj   = (t4 == 1.0f) ? 1.0f : 0.0f;
        const float noobj = (t4 == 0.0f) ? 1.0f : 0.0f;

        float d4 = pv[4] - t4;
        float d9 = pv[9] - tv[9];
        a_noobj += noobj * (d4 * d4 + d9 * d9);

        // target corners (faithful bug: x2 uses already-updated x1)
        float tw2 = tv[2] * tv[2], th2 = tv[3] * tv[3];
        float tx1 = tv[0] * CELL - 0.5f * tw2;
        float tx2 = tx1 * CELL + 0.5f * tw2;
        float ty1 = tv[1] * CELL - 0.5f * th2;
        float ty2 = ty1 * CELL + 0.5f * th2;
        float area_t = (tx2 - tx1) * (ty2 - ty1);

        float iou0, iou1;
        #pragma unroll
        for (int b = 0; b < 2; ++b) {
            float bw2 = pv[5 * b + 2] * pv[5 * b + 2];
            float bh2 = pv[5 * b + 3] * pv[5 * b + 3];
            float px1 = pv[5 * b + 0] * CELL - 0.5f * bw2;
            float px2 = px1 * CELL + 0.5f * bw2;
            float py1 = pv[5 * b + 1] * CELL - 0.5f * bh2;
            float py2 = py1 * CELL + 0.5f * bh2;
            float ltx = fmaxf(px1, tx1), lty = fmaxf(py1, ty1);
            float rbx = fminf(px2, tx2), rby = fminf(py2, ty2);
            float inter = fmaxf(rbx - ltx, 0.0f) * fmaxf(rby - lty, 0.0f);
            float area_p = (px2 - px1) * (py2 - py1);
            float iou = inter / (area_p + area_t - inter);
            if (b == 0) iou0 = iou; else iou1 = iou;
        }
        const bool b1 = (iou1 > iou0);   // jnp.argmax: first on ties

        float cpx = b1 ? pv[5] : pv[0], ctx = b1 ? tv[5] : tv[0];
        float cpy = b1 ? pv[6] : pv[1], cty = b1 ? tv[6] : tv[1];
        float cpw = b1 ? pv[7] : pv[2], ctw = b1 ? tv[7] : tv[2];
        float cph = b1 ? pv[8] : pv[3], cth = b1 ? tv[8] : tv[3];
        float cpc = b1 ? pv[9] : pv[4], ctc = b1 ? tv[9] : tv[4];

        float dx = cpx - ctx, dy = cpy - cty;
        float dw = cpw - ctw, dh = cph - cth;
        a_cw   += obj * (dx * dx + dy * dy + dw * dw + dh * dh);
        float dc = cpc - ctc;
        a_conf += obj * dc * dc;
        float dk = pk - best;
        a_cls  += obj * dk * dk;

        __syncthreads();                 // LDS consumed before next staging
    }

    // ---- block reduction: wave shuffle -> 2-wave LDS combine ----
    float vals[4] = { a_cls, a_conf, a_cw, a_noobj };
    #pragma unroll
    for (int c = 0; c < 4; ++c) {
        #pragma unroll
        for (int off = 32; off > 0; off >>= 1)
            vals[c] += __shfl_down(vals[c], off, 64);
    }
    const int wave = tid >> 6;
    if ((tid & 63) == 0) {
        red[0][wave] = vals[0]; red[1][wave] = vals[1];
        red[2][wave] = vals[2]; red[3][wave] = vals[3];
    }
    __syncthreads();
    if (tid == 0) {
        ws[blockIdx.x] = make_float4(red[0][0] + red[0][1],
                                     red[1][0] + red[1][1],
                                     red[2][0] + red[2][1],
                                     red[3][0] + red[3][1]);
    }
}

__launch_bounds__(1024, 1)
__global__ void yolo_reduce(const float4* __restrict__ ws, float* __restrict__ out)
{
    __shared__ float red[4][16];
    const int tid = threadIdx.x;

    float s0 = 0.f, s1 = 0.f, s2 = 0.f, s3 = 0.f;
    for (int b = tid; b < GRID; b += 1024) {    // coalesced float4 stream
        float4 v = ws[b];
        s0 += v.x; s1 += v.y; s2 += v.z; s3 += v.w;
    }
    float vals[4] = { s0, s1, s2, s3 };
    #pragma unroll
    for (int c = 0; c < 4; ++c) {
        #pragma unroll
        for (int off = 32; off > 0; off >>= 1)
            vals[c] += __shfl_down(vals[c], off, 64);
        if ((tid & 63) == 0) red[c][tid >> 6] = vals[c];
    }
    __syncthreads();
    if (tid == 0) {
        float t0 = 0.f, t1 = 0.f, t2 = 0.f, t3 = 0.f;
        #pragma unroll
        for (int w = 0; w < 16; ++w) {
            t0 += red[0][w]; t1 += red[1][w]; t2 += red[2][w]; t3 += red[3][w];
        }
        out[0] = LC * t0;                              // cls_loss
        out[1] = LC * t1;                              // conf_loss
        out[2] = LC * t2;                              // center+wh
        out[3] = LN * t3 + LC * (t0 + t1 + t2);        // total
    }
}

extern "C" void kernel_launch(void* const* d_in, const int* in_sizes, int n_in,
                              void* d_out, int out_size, void* d_ws, size_t ws_size,
                              hipStream_t stream) {
    const float* P = (const float*)d_in[0];
    const float* T = (const float*)d_in[1];
    float* out = (float*)d_out;
    float4* ws = (float4*)d_ws;          // GRID * 16 B = 50176 B of scratch

    yolo_partial<<<GRID, BLK, 0, stream>>>(P, T, ws);
    yolo_reduce<<<1, 1024, 0, stream>>>(ws, out);
}